// Round 1
// baseline (652.673 us; speedup 1.0000x reference)
//
#include <hip/hip_runtime.h>

typedef unsigned short u16;
typedef __attribute__((ext_vector_type(8))) short sh8;           // 8 bf16 (4 VGPR)
typedef __attribute__((ext_vector_type(8))) unsigned short us8;
typedef __attribute__((ext_vector_type(4))) float f4;

__device__ __forceinline__ float bf2f(u16 u) {
  union { unsigned u; float f; } v; v.u = ((unsigned)u) << 16; return v.f;
}
__device__ __forceinline__ u16 f2bf(float f) {
  union { float f; unsigned u; } v; v.f = f;
  unsigned r = v.u + 0x7fffu + ((v.u >> 16) & 1u);   // RNE, inputs finite
  return (u16)(r >> 16);
}

// ---------------- f32 -> bf16, 8 elems/thread ----------------
__global__ __launch_bounds__(256)
void k_cvt_bf16(const float* __restrict__ in, u16* __restrict__ out, int n8) {
  int idx = blockIdx.x * 256 + threadIdx.x;
  if (idx >= n8) return;
  const f4* p = (const f4*)in + (size_t)idx * 2;
  f4 a = p[0], b = p[1];
  us8 o;
  o[0] = f2bf(a[0]); o[1] = f2bf(a[1]); o[2] = f2bf(a[2]); o[3] = f2bf(a[3]);
  o[4] = f2bf(b[0]); o[5] = f2bf(b[1]); o[6] = f2bf(b[2]); o[7] = f2bf(b[3]);
  ((us8*)out)[idx] = o;
}

// ------- weights: concat + transpose to Wt[n][k] bf16, n in [0,6144) -------
// n<1024: Wq col n | 1024<=n<3072: Wl col n-1024 | 3072<=n<5120: Wc col n-3072
// | 5120<=n<6144: Wo col n-5120
__global__ __launch_bounds__(256)
void k_prep_w(const float* __restrict__ Wq, const float* __restrict__ Wl,
              const float* __restrict__ Wc, const float* __restrict__ Wo,
              u16* __restrict__ Wt) {
  __shared__ u16 tile[64][65];
  const int n0 = blockIdx.x * 64;
  const int k0 = blockIdx.y * 64;
  const float* src; int ld, col0;
  if (n0 < 1024)      { src = Wq; ld = 1024; col0 = n0; }
  else if (n0 < 3072) { src = Wl; ld = 2048; col0 = n0 - 1024; }
  else if (n0 < 5120) { src = Wc; ld = 2048; col0 = n0 - 3072; }
  else                { src = Wo; ld = 1024; col0 = n0 - 5120; }
  const int t = threadIdx.x;
  const int r = t >> 2;          // 0..63
  const int c0 = (t & 3) * 16;   // 0,16,32,48
  const float* sp = src + (size_t)(k0 + r) * ld + col0 + c0;
  #pragma unroll
  for (int j = 0; j < 16; j++) tile[r][c0 + j] = f2bf(sp[j]);
  __syncthreads();
  u16* op = Wt + (size_t)(n0 + r) * 1024 + k0 + c0;
  #pragma unroll
  for (int j = 0; j < 16; j++) op[j] = tile[c0 + j][r];
}

// ---------------- bf16 MFMA GEMM, A[M][K] * Bt[N][K]^T -> C[M][N] ----------------
// 128x128 tile, BK=64, 256 threads (4 waves, 2x2), 4x4 16x16x32 frags/wave.
template<bool OUT_BF16>
__global__ __launch_bounds__(256, 2)
void k_gemm_bt(const u16* __restrict__ A, const u16* __restrict__ Bt,
               void* __restrict__ Cout, int M, int N, int K) {
  constexpr int LDT = 72;  // 64 + 8 pad (bank-conflict spread, keeps 16B align)
  __shared__ __align__(16) u16 As[128 * LDT];
  __shared__ __align__(16) u16 Bs[128 * LDT];
  const int bm0 = blockIdx.y * 128;
  const int bn0 = blockIdx.x * 128;
  const int t = threadIdx.x;
  const int lane = t & 63;
  const int wave = t >> 6;
  const int wr = wave >> 1, wc = wave & 1;
  f4 acc[4][4] = {};
  const int sr = t >> 1;            // staging row 0..127
  const int sc = (t & 1) * 32;      // 32 bf16 per thread
  const u16* Ap = A + (size_t)(bm0 + sr) * K + sc;
  const u16* Bp = Bt + (size_t)(bn0 + sr) * K + sc;
  u16* AsW = &As[sr * LDT + sc];
  u16* BsW = &Bs[sr * LDT + sc];
  const int fr = lane & 15;
  const int ko = (lane >> 4) * 8;
  for (int kt = 0; kt < K; kt += 64) {
    sh8 a0 = *(const sh8*)(Ap + kt);
    sh8 a1 = *(const sh8*)(Ap + kt + 8);
    sh8 a2 = *(const sh8*)(Ap + kt + 16);
    sh8 a3 = *(const sh8*)(Ap + kt + 24);
    sh8 b0 = *(const sh8*)(Bp + kt);
    sh8 b1 = *(const sh8*)(Bp + kt + 8);
    sh8 b2 = *(const sh8*)(Bp + kt + 16);
    sh8 b3 = *(const sh8*)(Bp + kt + 24);
    __syncthreads();
    *(sh8*)(AsW) = a0; *(sh8*)(AsW + 8) = a1; *(sh8*)(AsW + 16) = a2; *(sh8*)(AsW + 24) = a3;
    *(sh8*)(BsW) = b0; *(sh8*)(BsW + 8) = b1; *(sh8*)(BsW + 16) = b2; *(sh8*)(BsW + 24) = b3;
    __syncthreads();
    #pragma unroll
    for (int kh = 0; kh < 2; kh++) {
      sh8 af[4], bfv[4];
      const int kofs = kh * 32 + ko;
      #pragma unroll
      for (int mi = 0; mi < 4; mi++)
        af[mi] = *(const sh8*)&As[(wr * 64 + mi * 16 + fr) * LDT + kofs];
      #pragma unroll
      for (int ni = 0; ni < 4; ni++)
        bfv[ni] = *(const sh8*)&Bs[(wc * 64 + ni * 16 + fr) * LDT + kofs];
      #pragma unroll
      for (int mi = 0; mi < 4; mi++)
        #pragma unroll
        for (int ni = 0; ni < 4; ni++)
          acc[mi][ni] = __builtin_amdgcn_mfma_f32_16x16x32_bf16(af[mi], bfv[ni], acc[mi][ni], 0, 0, 0);
    }
  }
  const int rbase = bm0 + wr * 64 + (lane >> 4) * 4;
  const int cbase = bn0 + wc * 64 + fr;
  #pragma unroll
  for (int mi = 0; mi < 4; mi++)
    #pragma unroll
    for (int ni = 0; ni < 4; ni++)
      #pragma unroll
      for (int r = 0; r < 4; r++) {
        const size_t off = (size_t)(rbase + mi * 16 + r) * N + (cbase + ni * 16);
        if constexpr (OUT_BF16) ((u16*)Cout)[off] = f2bf(acc[mi][ni][r]);
        else                    ((float*)Cout)[off] = acc[mi][ni][r];
      }
}

// ---------------- mean-pool kc/vc: 32-row windows, stride 16 ----------------
__global__ __launch_bounds__(64)
void k_pool(const u16* __restrict__ proj, float* __restrict__ kp, float* __restrict__ vp) {
  const int blk = blockIdx.x;
  const int j = blk % 127;
  const int bh = blk / 127;
  const int b = bh >> 4, h = bh & 15;
  const int d = threadIdx.x;
  const size_t base = (size_t)(b * 2048 + j * 16) * 5120;
  const size_t kcol = 3072 + h * 64 + d;
  const size_t vcol = 4096 + h * 64 + d;
  float ks = 0.f, vs = 0.f;
  #pragma unroll 4
  for (int r = 0; r < 32; r++) {
    const size_t off = base + (size_t)r * 5120;
    ks += bf2f(proj[off + kcol]);
    vs += bf2f(proj[off + vcol]);
  }
  kp[((size_t)bh * 127 + j) * 64 + d] = ks * (1.f / 32.f);
  vp[((size_t)bh * 127 + j) * 64 + d] = vs * (1.f / 32.f);
}

// ---------------- attention: lane-per-query, online softmax, 8-key chunks ----------------
__global__ __launch_bounds__(64, 1)
void k_attn(const u16* __restrict__ proj, const float* __restrict__ kp,
            const float* __restrict__ vp, u16* __restrict__ yb) {
  const int blk = blockIdx.x;       // 1024 blocks
  const int qt = blk & 31;
  const int bh = blk >> 5;
  const int b = bh >> 4, h = bh & 15;
  const int lane = threadIdx.x;
  const int i = qt * 64 + lane;     // query index
  const size_t LDP = 5120;
  const u16* qp = proj + (size_t)(b * 2048 + i) * LDP + h * 64;
  float q[64];
  #pragma unroll
  for (int c = 0; c < 8; c++) {
    us8 v = *(const us8*)(qp + c * 8);
    #pragma unroll
    for (int jj = 0; jj < 8; jj++) q[c * 8 + jj] = bf2f(v[jj]) * 0.125f;  // fold 1/sqrt(hs)
  }
  float o[64];
  #pragma unroll
  for (int d = 0; d < 64; d++) o[d] = 0.f;
  float m = -1e30f, l = 0.f;

  // ---- phase 1: local windowed causal (j in (i-128, i]) ----
  const int q0 = qt * 64;
  const u16* kbase = proj + (size_t)(b * 2048) * LDP + 1024 + h * 64;
  const u16* vbase = proj + (size_t)(b * 2048) * LDP + 2048 + h * 64;
  int jstart = q0 - 127; if (jstart < 0) jstart = 0;
  const int jend = q0 + 63;
  for (int jc = jstart; jc <= jend; jc += 8) {
    float s[8];
    #pragma unroll
    for (int cc = 0; cc < 8; cc++) {
      const int j = jc + cc;
      const int jr = j < 2047 ? j : 2047;
      const u16* kr = kbase + (size_t)jr * LDP;
      float s0 = 0.f, s1 = 0.f, s2 = 0.f, s3 = 0.f;
      #pragma unroll
      for (int d8 = 0; d8 < 8; d8++) {
        us8 kv = *(const us8*)(kr + d8 * 8);
        s0 += q[d8 * 8 + 0] * bf2f(kv[0]);
        s1 += q[d8 * 8 + 1] * bf2f(kv[1]);
        s2 += q[d8 * 8 + 2] * bf2f(kv[2]);
        s3 += q[d8 * 8 + 3] * bf2f(kv[3]);
        s0 += q[d8 * 8 + 4] * bf2f(kv[4]);
        s1 += q[d8 * 8 + 5] * bf2f(kv[5]);
        s2 += q[d8 * 8 + 6] * bf2f(kv[6]);
        s3 += q[d8 * 8 + 7] * bf2f(kv[7]);
      }
      const bool ok = (j <= i) && (j > i - 128);
      s[cc] = ok ? (s0 + s1) + (s2 + s3) : -1e30f;
    }
    float cm = fmaxf(fmaxf(fmaxf(s[0], s[1]), fmaxf(s[2], s[3])),
                     fmaxf(fmaxf(s[4], s[5]), fmaxf(s[6], s[7])));
    const float mnew = fmaxf(m, cm);
    const float corr = __expf(m - mnew);   // m,mnew finite (-1e30 sentinel): no NaN
    l *= corr;
    #pragma unroll
    for (int d = 0; d < 64; d++) o[d] *= corr;
    float p[8];
    #pragma unroll
    for (int cc = 0; cc < 8; cc++) p[cc] = __expf(s[cc] - mnew);
    l += ((p[0] + p[1]) + (p[2] + p[3])) + ((p[4] + p[5]) + (p[6] + p[7]));
    #pragma unroll
    for (int cc = 0; cc < 8; cc++) {
      const int j = jc + cc;
      const int jr = j < 2047 ? j : 2047;
      const u16* vr = vbase + (size_t)jr * LDP;
      const float pc = p[cc];
      #pragma unroll
      for (int d8 = 0; d8 < 8; d8++) {
        us8 vv = *(const us8*)(vr + d8 * 8);
        #pragma unroll
        for (int jj = 0; jj < 8; jj++) o[d8 * 8 + jj] += pc * bf2f(vv[jj]);
      }
    }
    m = mnew;
  }
  u16* yrow = yb + (size_t)(b * 2048 + i) * 1024 + h * 64;
  {
    const float invl = 1.f / l;   // l>0: key j=i always allowed
    #pragma unroll
    for (int c = 0; c < 8; c++) {
      us8 vo;
      #pragma unroll
      for (int jj = 0; jj < 8; jj++) vo[jj] = f2bf(o[c * 8 + jj] * invl);
      *(us8*)(yrow + c * 8) = vo;   // park y_local; re-read after comp phase (same thread)
    }
  }

  // ---- phase 2: compressed blocks (16*j <= i), n_def==0 for T=2048 ----
  #pragma unroll
  for (int d = 0; d < 64; d++) o[d] = 0.f;
  m = -1e30f; l = 0.f;
  const float* kpb = kp + (size_t)bh * 127 * 64;
  const float* vpb = vp + (size_t)bh * 127 * 64;
  for (int jc = 0; jc < 127; jc += 8) {
    float s[8];
    #pragma unroll
    for (int cc = 0; cc < 8; cc++) {
      const int j = jc + cc;
      const int jr = j < 126 ? j : 126;
      const float* kr = kpb + (size_t)jr * 64;
      float s0 = 0.f, s1 = 0.f, s2 = 0.f, s3 = 0.f;
      #pragma unroll
      for (int d4 = 0; d4 < 16; d4++) {
        f4 kv = *(const f4*)(kr + d4 * 4);
        s0 += q[d4 * 4 + 0] * kv[0];
        s1 += q[d4 * 4 + 1] * kv[1];
        s2 += q[d4 * 4 + 2] * kv[2];
        s3 += q[d4 * 4 + 3] * kv[3];
      }
      const bool ok = (j < 127) && (16 * j <= i);
      s[cc] = ok ? (s0 + s1) + (s2 + s3) : -1e30f;
    }
    float cm = fmaxf(fmaxf(fmaxf(s[0], s[1]), fmaxf(s[2], s[3])),
                     fmaxf(fmaxf(s[4], s[5]), fmaxf(s[6], s[7])));
    const float mnew = fmaxf(m, cm);
    const float corr = __expf(m - mnew);
    l *= corr;
    #pragma unroll
    for (int d = 0; d < 64; d++) o[d] *= corr;
    float p[8];
    #pragma unroll
    for (int cc = 0; cc < 8; cc++) p[cc] = __expf(s[cc] - mnew);
    l += ((p[0] + p[1]) + (p[2] + p[3])) + ((p[4] + p[5]) + (p[6] + p[7]));
    #pragma unroll
    for (int cc = 0; cc < 8; cc++) {
      const int j = jc + cc;
      const int jr = j < 126 ? j : 126;
      const float* vr = vpb + (size_t)jr * 64;
      const float pc = p[cc];
      #pragma unroll
      for (int d4 = 0; d4 < 16; d4++) {
        f4 vv = *(const f4*)(vr + d4 * 4);
        #pragma unroll
        for (int jj = 0; jj < 4; jj++) o[d4 * 4 + jj] += pc * vv[jj];
      }
    }
    m = mnew;
  }
  {
    const float invl = 1.f / l;   // l>0: block 0 always allowed
    #pragma unroll
    for (int c = 0; c < 8; c++) {
      us8 yv = *(const us8*)(yrow + c * 8);
      us8 vo;
      #pragma unroll
      for (int jj = 0; jj < 8; jj++)
        vo[jj] = f2bf(bf2f(yv[jj]) + o[c * 8 + jj] * invl);
      *(us8*)(yrow + c * 8) = vo;
    }
  }
}

extern "C" void kernel_launch(void* const* d_in, const int* in_sizes, int n_in,
                              void* d_out, int out_size, void* d_ws, size_t ws_size,
                              hipStream_t stream) {
  const float* x  = (const float*)d_in[0];
  const float* Wq = (const float*)d_in[1];
  const float* Wl = (const float*)d_in[2];
  const float* Wc = (const float*)d_in[3];
  const float* Wo = (const float*)d_in[4];
  // d_in[5]=dkc, d_in[6]=dvc: unused — n_def == 0 when T=2048.
  float* out = (float*)d_out;
  char* ws = (char*)d_ws;
  // workspace layout (all 16B-aligned offsets), total ~70 MB
  u16*   xb   = (u16*)(ws);                       //  8,388,608 B: x bf16 [4096][1024]
  u16*   Wt   = (u16*)(ws + 8388608);             // 12,582,912 B: weights^T bf16 [6144][1024]
  u16*   proj = (u16*)(ws + 20971520);            // 41,943,040 B: [4096][5120] q|kl|vl|kc|vc bf16
  float* kp   = (float*)(ws + 62914560);          //  1,040,384 B: pooled K [32][127][64] f32
  float* vp   = (float*)(ws + 63954944);          //  1,040,384 B: pooled V
  u16*   yb   = (u16*)(ws + 64995328);            //  8,388,608 B: y bf16 [4096][1024]

  k_cvt_bf16<<<2048, 256, 0, stream>>>(x, xb, 4194304 / 8);
  k_prep_w<<<dim3(96, 16), 256, 0, stream>>>(Wq, Wl, Wc, Wo, Wt);
  k_gemm_bt<true><<<dim3(40, 32), 256, 0, stream>>>(xb, Wt, proj, 4096, 5120, 1024);
  k_pool<<<32 * 127, 64, 0, stream>>>(proj, kp, vp);
  k_attn<<<1024, 64, 0, stream>>>(proj, kp, vp, yb);
  k_gemm_bt<false><<<dim3(8, 32), 256, 0, stream>>>(yb, Wt + (size_t)5120 * 1024, out, 4096, 1024, 1024);
}

// Round 2
// 169.153 us; speedup vs baseline: 3.8585x; 3.8585x over previous
//
#include <hip/hip_runtime.h>

typedef unsigned short u16;
typedef __attribute__((ext_vector_type(8))) short sh8;           // 8 bf16 (4 VGPR)
typedef __attribute__((ext_vector_type(8))) unsigned short us8;
typedef __attribute__((ext_vector_type(4))) float f4;

__device__ __forceinline__ float bf2f(u16 u) {
  union { unsigned u; float f; } v; v.u = ((unsigned)u) << 16; return v.f;
}
__device__ __forceinline__ u16 f2bf(float f) {
  union { float f; unsigned u; } v; v.f = f;
  unsigned r = v.u + 0x7fffu + ((v.u >> 16) & 1u);   // RNE, inputs finite
  return (u16)(r >> 16);
}

// ---------------- f32 -> bf16, 8 elems/thread ----------------
__global__ __launch_bounds__(256)
void k_cvt_bf16(const float* __restrict__ in, u16* __restrict__ out, int n8) {
  int idx = blockIdx.x * 256 + threadIdx.x;
  if (idx >= n8) return;
  const f4* p = (const f4*)in + (size_t)idx * 2;
  f4 a = p[0], b = p[1];
  us8 o;
  o[0] = f2bf(a[0]); o[1] = f2bf(a[1]); o[2] = f2bf(a[2]); o[3] = f2bf(a[3]);
  o[4] = f2bf(b[0]); o[5] = f2bf(b[1]); o[6] = f2bf(b[2]); o[7] = f2bf(b[3]);
  ((us8*)out)[idx] = o;
}

// ------- weights: concat + transpose to Wt[n][k] bf16, n in [0,6144) -------
__global__ __launch_bounds__(256)
void k_prep_w(const float* __restrict__ Wq, const float* __restrict__ Wl,
              const float* __restrict__ Wc, const float* __restrict__ Wo,
              u16* __restrict__ Wt) {
  __shared__ u16 tile[64][65];
  const int n0 = blockIdx.x * 64;
  const int k0 = blockIdx.y * 64;
  const float* src; int ld, col0;
  if (n0 < 1024)      { src = Wq; ld = 1024; col0 = n0; }
  else if (n0 < 3072) { src = Wl; ld = 2048; col0 = n0 - 1024; }
  else if (n0 < 5120) { src = Wc; ld = 2048; col0 = n0 - 3072; }
  else                { src = Wo; ld = 1024; col0 = n0 - 5120; }
  const int t = threadIdx.x;
  const int r = t >> 2;          // 0..63
  const int c0 = (t & 3) * 16;   // 0,16,32,48
  const float* sp = src + (size_t)(k0 + r) * ld + col0 + c0;
  #pragma unroll
  for (int j = 0; j < 16; j++) tile[r][c0 + j] = f2bf(sp[j]);
  __syncthreads();
  u16* op = Wt + (size_t)(n0 + r) * 1024 + k0 + c0;
  #pragma unroll
  for (int j = 0; j < 16; j++) op[j] = tile[c0 + j][r];
}

// ---------------- bf16 MFMA GEMM, A[M][K] * Bt[N][K]^T -> C[M][N] ----------------
template<bool OUT_BF16>
__global__ __launch_bounds__(256, 2)
void k_gemm_bt(const u16* __restrict__ A, const u16* __restrict__ Bt,
               void* __restrict__ Cout, int M, int N, int K) {
  constexpr int LDT = 72;
  __shared__ __align__(16) u16 As[128 * LDT];
  __shared__ __align__(16) u16 Bs[128 * LDT];
  const int bm0 = blockIdx.y * 128;
  const int bn0 = blockIdx.x * 128;
  const int t = threadIdx.x;
  const int lane = t & 63;
  const int wave = t >> 6;
  const int wr = wave >> 1, wc = wave & 1;
  f4 acc[4][4] = {};
  const int sr = t >> 1;
  const int sc = (t & 1) * 32;
  const u16* Ap = A + (size_t)(bm0 + sr) * K + sc;
  const u16* Bp = Bt + (size_t)(bn0 + sr) * K + sc;
  u16* AsW = &As[sr * LDT + sc];
  u16* BsW = &Bs[sr * LDT + sc];
  const int fr = lane & 15;
  const int ko = (lane >> 4) * 8;
  for (int kt = 0; kt < K; kt += 64) {
    sh8 a0 = *(const sh8*)(Ap + kt);
    sh8 a1 = *(const sh8*)(Ap + kt + 8);
    sh8 a2 = *(const sh8*)(Ap + kt + 16);
    sh8 a3 = *(const sh8*)(Ap + kt + 24);
    sh8 b0 = *(const sh8*)(Bp + kt);
    sh8 b1 = *(const sh8*)(Bp + kt + 8);
    sh8 b2 = *(const sh8*)(Bp + kt + 16);
    sh8 b3 = *(const sh8*)(Bp + kt + 24);
    __syncthreads();
    *(sh8*)(AsW) = a0; *(sh8*)(AsW + 8) = a1; *(sh8*)(AsW + 16) = a2; *(sh8*)(AsW + 24) = a3;
    *(sh8*)(BsW) = b0; *(sh8*)(BsW + 8) = b1; *(sh8*)(BsW + 16) = b2; *(sh8*)(BsW + 24) = b3;
    __syncthreads();
    #pragma unroll
    for (int kh = 0; kh < 2; kh++) {
      sh8 af[4], bfv[4];
      const int kofs = kh * 32 + ko;
      #pragma unroll
      for (int mi = 0; mi < 4; mi++)
        af[mi] = *(const sh8*)&As[(wr * 64 + mi * 16 + fr) * LDT + kofs];
      #pragma unroll
      for (int ni = 0; ni < 4; ni++)
        bfv[ni] = *(const sh8*)&Bs[(wc * 64 + ni * 16 + fr) * LDT + kofs];
      #pragma unroll
      for (int mi = 0; mi < 4; mi++)
        #pragma unroll
        for (int ni = 0; ni < 4; ni++)
          acc[mi][ni] = __builtin_amdgcn_mfma_f32_16x16x32_bf16(af[mi], bfv[ni], acc[mi][ni], 0, 0, 0);
    }
  }
  const int rbase = bm0 + wr * 64 + (lane >> 4) * 4;
  const int cbase = bn0 + wc * 64 + fr;
  #pragma unroll
  for (int mi = 0; mi < 4; mi++)
    #pragma unroll
    for (int ni = 0; ni < 4; ni++)
      #pragma unroll
      for (int r = 0; r < 4; r++) {
        const size_t off = (size_t)(rbase + mi * 16 + r) * N + (cbase + ni * 16);
        if constexpr (OUT_BF16) ((u16*)Cout)[off] = f2bf(acc[mi][ni][r]);
        else                    ((float*)Cout)[off] = acc[mi][ni][r];
      }
}

// ---- mean-pool kc/vc -> kpb[bh][128][64] bf16, vpT[bh][64][128] bf16 (pad zeroed) ----
__global__ __launch_bounds__(64)
void k_pool(const u16* __restrict__ proj, u16* __restrict__ kpb, u16* __restrict__ vpT) {
  const int j = blockIdx.x;    // 0..127 (127 = zero pad)
  const int bh = blockIdx.y;   // 0..31
  const int b = bh >> 4, h = bh & 15;
  const int d = threadIdx.x;
  u16 kout = 0, vout = 0;
  if (j < 127) {
    const size_t base = (size_t)(b * 2048 + j * 16) * 5120;
    const size_t kcol = 3072 + h * 64 + d;
    const size_t vcol = 4096 + h * 64 + d;
    float ks = 0.f, vs = 0.f;
    #pragma unroll 4
    for (int r = 0; r < 32; r++) {
      const size_t off = base + (size_t)r * 5120;
      ks += bf2f(proj[off + kcol]);
      vs += bf2f(proj[off + vcol]);
    }
    kout = f2bf(ks * (1.f / 32.f));
    vout = f2bf(vs * (1.f / 32.f));
  }
  kpb[((size_t)bh * 128 + j) * 64 + d] = kout;
  vpT[((size_t)bh * 64 + d) * 128 + j] = vout;
}

// ---- transpose vl: proj cols [2048,3072) -> vlT[bh][64 d][2048 t] bf16 ----
__global__ __launch_bounds__(256)
void k_vt(const u16* __restrict__ proj, u16* __restrict__ vlT) {
  __shared__ u16 tile[64][72];
  const int tt = blockIdx.x;   // 0..31 token tile
  const int bh = blockIdx.y;   // 0..31
  const int b = bh >> 4, h = bh & 15;
  const int t = threadIdx.x;
  const int r = t >> 2;          // 0..63
  const int c0 = (t & 3) * 16;
  const u16* sp = proj + (size_t)(b * 2048 + tt * 64 + r) * 5120 + 2048 + h * 64 + c0;
  us8 v0 = *(const us8*)sp;
  us8 v1 = *(const us8*)(sp + 8);
  #pragma unroll
  for (int jj = 0; jj < 8; jj++) { tile[r][c0 + jj] = v0[jj]; tile[r][c0 + 8 + jj] = v1[jj]; }
  __syncthreads();
  u16* op = vlT + ((size_t)bh * 64 + r) * 2048 + tt * 64 + c0;
  #pragma unroll
  for (int jj = 0; jj < 16; jj++) op[jj] = tile[c0 + jj][r];
}

// ---------------- MFMA attention ----------------
// Block = (qtile of 64, bh). 4 waves x 16 queries. Per wave:
//   S^T = mfma(K rows, Q rows)  -> D: row=key=(g*4+reg), col=q=fr   (verified conv)
//   mask -> softmax (shfl_xor 16,32 over g-groups) -> P/l -> bf16 -> per-wave LDS
//   Y   = mfma(P rows (A from LDS), V^T rows (Bt from vlT/vpT))
__global__ __launch_bounds__(256)
void k_attn_mfma(const u16* __restrict__ proj, const u16* __restrict__ kpb,
                 const u16* __restrict__ vpT, const u16* __restrict__ vlT,
                 u16* __restrict__ yb) {
  constexpr int LDS_P = 200;   // u16; row stride 400B (16B-aligned)
  __shared__ __align__(16) u16 P[4][16][LDS_P];
  const int qt = blockIdx.x;          // 0..31
  const int bh = blockIdx.y;          // 0..31
  const int b = bh >> 4, h = bh & 15;
  const int tid = threadIdx.x;
  const int wave = tid >> 6;
  const int lane = tid & 63;
  const int fr = lane & 15;
  const int g  = lane >> 4;
  const int ko = g * 8;
  const int q0 = qt * 64;
  const int qq = wave * 16 + fr;       // q-in-tile for this lane's column
  const int i_abs = q0 + qq;
  const int kbase = q0 - 128;          // local key range: j = kbase + kk, kk in [0,192)
  const int kmin = q0 >= 128 ? 0 : 128 - q0;   // kk >= kmin <=> j >= 0

  const u16* prow = proj + (size_t)(b * 2048) * 5120;
  const sh8 bq0 = *(const sh8*)(prow + (size_t)i_abs * 5120 + h * 64 + ko);
  const sh8 bq1 = *(const sh8*)(prow + (size_t)i_abs * 5120 + h * 64 + 32 + ko);

  // ===== local phase: 192 keys =====
  f4 st[12];
  #pragma unroll
  for (int f = 0; f < 12; f++) st[f] = f4{0.f, 0.f, 0.f, 0.f};
  const u16* klb = prow + 1024 + h * 64;
  #pragma unroll
  for (int kh = 0; kh < 2; kh++) {
    const sh8 bq = kh ? bq1 : bq0;
    #pragma unroll
    for (int f = 0; f < 12; f++) {
      int krow = kbase + f * 16 + fr; if (krow < 0) krow = 0;  // masked rows clamped
      sh8 ak = *(const sh8*)(klb + (size_t)krow * 5120 + kh * 32 + ko);
      st[f] = __builtin_amdgcn_mfma_f32_16x16x32_bf16(ak, bq, st[f], 0, 0, 0);
    }
  }
  float m = -1e30f;
  #pragma unroll
  for (int f = 0; f < 12; f++)
    #pragma unroll
    for (int r = 0; r < 4; r++) {
      const int kk = f * 16 + g * 4 + r;
      const bool ok = (kk > qq) && (kk <= qq + 128) && (kk >= kmin);
      const float v = ok ? st[f][r] * 0.125f : -1e30f;
      st[f][r] = v; m = fmaxf(m, v);
    }
  m = fmaxf(m, __shfl_xor(m, 16));
  m = fmaxf(m, __shfl_xor(m, 32));
  float l = 0.f;
  #pragma unroll
  for (int f = 0; f < 12; f++)
    #pragma unroll
    for (int r = 0; r < 4; r++) {
      const float p = __expf(st[f][r] - m);
      st[f][r] = p; l += p;
    }
  l += __shfl_xor(l, 16);
  l += __shfl_xor(l, 32);
  {
    const float inv = 1.f / l;     // l>0: key j=i always in-window
    #pragma unroll
    for (int f = 0; f < 12; f++)
      #pragma unroll
      for (int r = 0; r < 4; r++)
        P[wave][fr][f * 16 + g * 4 + r] = f2bf(st[f][r] * inv);
  }
  f4 yacc[4];
  #pragma unroll
  for (int ni = 0; ni < 4; ni++) yacc[ni] = f4{0.f, 0.f, 0.f, 0.f};
  const u16* vt = vlT + (size_t)bh * 64 * 2048;
  #pragma unroll
  for (int ks = 0; ks < 6; ks++) {
    sh8 pa = *(const sh8*)&P[wave][fr][ks * 32 + ko];
    int kj = kbase + ks * 32 + ko; if (kj < 0) kj = 0;  // fully-masked 8-key span
    #pragma unroll
    for (int ni = 0; ni < 4; ni++) {
      sh8 vb = *(const sh8*)(vt + (size_t)(ni * 16 + fr) * 2048 + kj);
      yacc[ni] = __builtin_amdgcn_mfma_f32_16x16x32_bf16(pa, vb, yacc[ni], 0, 0, 0);
    }
  }

  // ===== compressed phase: nf*16 pooled keys (wave-uniform skip of masked tail) =====
  int nf = ((q0 + 63) >> 8) + 1;   // frags with any allowed block
  nf = (nf + 1) & ~1;              // even, <= 8
  f4 sc[8];
  #pragma unroll
  for (int f = 0; f < 8; f++) sc[f] = f4{0.f, 0.f, 0.f, 0.f};
  const u16* kpr = kpb + (size_t)bh * 128 * 64;
  #pragma unroll
  for (int kh = 0; kh < 2; kh++) {
    const sh8 bq = kh ? bq1 : bq0;
    #pragma unroll
    for (int f = 0; f < 8; f++)
      if (f < nf) {
        sh8 ak = *(const sh8*)(kpr + (size_t)(f * 16 + fr) * 64 + kh * 32 + ko);
        sc[f] = __builtin_amdgcn_mfma_f32_16x16x32_bf16(ak, bq, sc[f], 0, 0, 0);
      }
  }
  float m2 = -1e30f;
  #pragma unroll
  for (int f = 0; f < 8; f++)
    #pragma unroll
    for (int r = 0; r < 4; r++) {
      const int jj = f * 16 + g * 4 + r;
      const bool ok = (jj <= 126) && (16 * jj <= i_abs);
      const float v = ok ? sc[f][r] * 0.125f : -1e30f;
      sc[f][r] = v; m2 = fmaxf(m2, v);
    }
  m2 = fmaxf(m2, __shfl_xor(m2, 16));
  m2 = fmaxf(m2, __shfl_xor(m2, 32));
  float l2 = 0.f;
  #pragma unroll
  for (int f = 0; f < 8; f++)
    #pragma unroll
    for (int r = 0; r < 4; r++) {
      const float p = __expf(sc[f][r] - m2);
      sc[f][r] = p; l2 += p;
    }
  l2 += __shfl_xor(l2, 16);
  l2 += __shfl_xor(l2, 32);
  {
    const float inv2 = 1.f / l2;   // l2>0: block 0 allowed for every i
    #pragma unroll
    for (int f = 0; f < 8; f++)
      if (f < nf)
        #pragma unroll
        for (int r = 0; r < 4; r++)
          P[wave][fr][f * 16 + g * 4 + r] = f2bf(sc[f][r] * inv2);
  }
  const u16* vpt = vpT + (size_t)bh * 64 * 128;
  const int nks = nf >> 1;
  #pragma unroll
  for (int ks = 0; ks < 4; ks++)
    if (ks < nks) {
      sh8 pa = *(const sh8*)&P[wave][fr][ks * 32 + ko];
      #pragma unroll
      for (int ni = 0; ni < 4; ni++) {
        sh8 vb = *(const sh8*)(vpt + (size_t)(ni * 16 + fr) * 128 + ks * 32 + ko);
        yacc[ni] = __builtin_amdgcn_mfma_f32_16x16x32_bf16(pa, vb, yacc[ni], 0, 0, 0);
      }
    }

  // ===== write y = y_local + y_comp (both pre-normalized) =====
  u16* yr = yb + (size_t)(b * 2048 + q0 + wave * 16 + g * 4) * 1024 + h * 64 + fr;
  #pragma unroll
  for (int ni = 0; ni < 4; ni++)
    #pragma unroll
    for (int r = 0; r < 4; r++)
      yr[(size_t)r * 1024 + ni * 16] = f2bf(yacc[ni][r]);
}

extern "C" void kernel_launch(void* const* d_in, const int* in_sizes, int n_in,
                              void* d_out, int out_size, void* d_ws, size_t ws_size,
                              hipStream_t stream) {
  const float* x  = (const float*)d_in[0];
  const float* Wq = (const float*)d_in[1];
  const float* Wl = (const float*)d_in[2];
  const float* Wc = (const float*)d_in[3];
  const float* Wo = (const float*)d_in[4];
  // dkc/dvc unused: n_def == 0 at T=2048.
  float* out = (float*)d_out;
  char* ws = (char*)d_ws;
  // workspace (72.4 MB): vlT aliases xb (xb dead after gemm1)
  u16* xb   = (u16*)(ws);                       //  8 MB  x bf16 [4096][1024]
  u16* vlT  = (u16*)(ws);                       //  8 MB  vl^T bf16 [32][64][2048] (after gemm1)
  u16* Wt   = (u16*)(ws + 8388608);             // 12 MB  weights^T bf16 [6144][1024]
  u16* proj = (u16*)(ws + 20971520);            // 40 MB  [4096][5120] q|kl|vl|kc|vc
  u16* kpb  = (u16*)(ws + 62914560);            // 512 KB pooled K bf16 [32][128][64]
  u16* vpT  = (u16*)(ws + 63438848);            // 512 KB pooled V^T bf16 [32][64][128]
  u16* yb   = (u16*)(ws + 63963136);            //  8 MB  y bf16 [4096][1024]

  k_cvt_bf16<<<2048, 256, 0, stream>>>(x, xb, 4194304 / 8);
  k_prep_w<<<dim3(96, 16), 256, 0, stream>>>(Wq, Wl, Wc, Wo, Wt);
  k_gemm_bt<true><<<dim3(40, 32), 256, 0, stream>>>(xb, Wt, proj, 4096, 5120, 1024);
  k_pool<<<dim3(128, 32), 64, 0, stream>>>(proj, kpb, vpT);
  k_vt<<<dim3(32, 32), 256, 0, stream>>>(proj, vlT);
  k_attn_mfma<<<dim3(32, 32), 256, 0, stream>>>(proj, kpb, vpT, vlT, yb);
  k_gemm_bt<false><<<dim3(8, 32), 256, 0, stream>>>(yb, Wt + (size_t)5120 * 1024, out, 4096, 1024, 1024);
}